// Round 1
// baseline (2122.867 us; speedup 1.0000x reference)
//
#include <hip/hip_runtime.h>

// ---------------------------------------------------------------------------
// FlowMatchingShield: 50-step Euler sampler over a 5-layer MLP.
//   h = concat([state(254), x(2), temb(64)])  -> 320
//   h @ W0 split:  base = state@W0[0:254]+b0  (once)
//                  tvec[s] = temb(s)@W0[256:320] (once, 50 vectors)
//                  x-part = x@W0[254:256]  (elementwise per step)
//   per step: 3x (1024x1024x1024) GEMM+SiLU  [bf16 MFMA]
//             + head W4 (1024->2) + Euler update + next h0  [fp32 fused tail]
//
// GEMM design (this round): 64x64 tile per 256-thread block, grid 16x16=256
// blocks (1/CU). K split across the 4 waves (256 each). Fragments are loaded
// DIRECTLY global->register (the 16x16x32 frag is one u16x8 per lane at
// row=lr, k=quad*8 — 64B-contiguous per 4-lane group), so the main loop has
// no LDS and no barriers. 3-buffer register prefetch (depth 2) hides L2
// latency under 16 MFMA/iter. Final cross-wave reduction via 34.8KB LDS in
// two 32-row phases, fused bias+SiLU, coalesced stores.
// ---------------------------------------------------------------------------

typedef __bf16 bf16x8 __attribute__((ext_vector_type(8)));
typedef float  f32x4  __attribute__((ext_vector_type(4)));
typedef unsigned short u16;
typedef u16 u16x8 __attribute__((ext_vector_type(8)));
typedef u16 u16x4 __attribute__((ext_vector_type(4)));

#define H 1024
#define BATCH 1024
#define SDIM 254
#define NSTEP 50
#define DT 0.02f

__device__ __forceinline__ u16 f2bf(float f) {
  unsigned int u = __float_as_uint(f);
  return (u16)((u + 0x7FFFu + ((u >> 16) & 1u)) >> 16);
}

__device__ __forceinline__ float silu(float v) {
  return v / (1.0f + __expf(-v));
}

// --- one-time: W[k][n] fp32 -> WT[n][k] bf16, for W1..W3 (blockIdx.z picks) --
__global__ void transpose_w(const float* __restrict__ A, const float* __restrict__ B,
                            const float* __restrict__ C, u16* __restrict__ TA,
                            u16* __restrict__ TB, u16* __restrict__ TC) {
  const float* W = (blockIdx.z == 0) ? A : (blockIdx.z == 1) ? B : C;
  u16* T = (blockIdx.z == 0) ? TA : (blockIdx.z == 1) ? TB : TC;
  __shared__ float tile[32][33];
  const int n0 = blockIdx.x * 32, k0 = blockIdx.y * 32;
  const int tx = threadIdx.x & 31, ty = threadIdx.x >> 5;  // 32 x 8
#pragma unroll
  for (int i = 0; i < 4; ++i)
    tile[ty + 8 * i][tx] = W[(k0 + ty + 8 * i) * H + n0 + tx];
  __syncthreads();
#pragma unroll
  for (int i = 0; i < 4; ++i)
    T[(size_t)(n0 + ty + 8 * i) * H + k0 + tx] = f2bf(tile[tx][ty + 8 * i]);
}

// --- one-time: base[b][n] = b0[n] + sum_k state[b][k]*W0[k][n] (k<254) -------
// 8 batch rows per block so each W0 float4 load feeds 8 FMAs (was 1): W0
// refetch traffic drops 1GB -> 128MB.
__global__ void base_gemm(const float* __restrict__ state, const float* __restrict__ W0,
                          const float* __restrict__ b0, float* __restrict__ base) {
  __shared__ float srow[8][SDIM];
  const int bx = blockIdx.x, by = blockIdx.y, tid = threadIdx.x;  // 128 threads
  for (int i = tid; i < 8 * SDIM; i += 128)
    srow[i / SDIM][i % SDIM] = state[(size_t)(by * 8 + i / SDIM) * SDIM + i % SDIM];
  __syncthreads();
  const int n = bx * 512 + tid * 4;
  float4 bv = *(const float4*)&b0[n];
  f32x4 a[8];
#pragma unroll
  for (int r = 0; r < 8; ++r) { a[r][0] = bv.x; a[r][1] = bv.y; a[r][2] = bv.z; a[r][3] = bv.w; }
  for (int k = 0; k < SDIM; ++k) {
    float4 wv = *(const float4*)&W0[(size_t)k * H + n];
#pragma unroll
    for (int r = 0; r < 8; ++r) {
      float s = srow[r][k];
      a[r][0] += s * wv.x; a[r][1] += s * wv.y; a[r][2] += s * wv.z; a[r][3] += s * wv.w;
    }
  }
#pragma unroll
  for (int r = 0; r < 8; ++r)
    *(f32x4*)&base[(size_t)(by * 8 + r) * H + n] = a[r];
}

// --- one-time: tvec[s][h] = sum_j sin(t fj) W0[256+j][h] + cos(t fj) W0[288+j][h]
__global__ void tvec_kernel(const float* __restrict__ W0, float* __restrict__ tvec) {
  const int s = blockIdx.x;
  const int h = blockIdx.y * 256 + threadIdx.x;
  const float t = (float)s * DT;
  float acc = 0.0f;
#pragma unroll
  for (int j = 0; j < 32; ++j) {
    float fr = __expf((float)j * (-9.210340371976184f / 31.0f));
    float ang = t * fr;
    acc += __sinf(ang) * W0[(256 + j) * H + h] + __cosf(ang) * W0[(288 + j) * H + h];
  }
  tvec[s * H + h] = acc;
}

// --- one-time: h0 for step 0 (bf16) + seed x into d_out ----------------------
__global__ void init_kernel(const float* __restrict__ base, const float* __restrict__ tvec,
                            const float* __restrict__ x0, const float* __restrict__ W0,
                            u16* __restrict__ h0, float* __restrict__ xout) {
  const int b = blockIdx.x, tid = threadIdx.x;
  const float xa = x0[2 * b], xb = x0[2 * b + 1];
  if (tid == 0) { xout[2 * b] = xa; xout[2 * b + 1] = xb; }
  const int n = tid * 4;
  float4 bs = *(const float4*)&base[(size_t)b * H + n];
  float4 tv = *(const float4*)&tvec[n];
  float4 wa = *(const float4*)&W0[254 * H + n];
  float4 wb = *(const float4*)&W0[255 * H + n];
  u16x4 r;
  r[0] = f2bf(silu(bs.x + tv.x + xa * wa.x + xb * wb.x));
  r[1] = f2bf(silu(bs.y + tv.y + xa * wa.y + xb * wb.y));
  r[2] = f2bf(silu(bs.z + tv.z + xa * wa.z + xb * wb.z));
  r[3] = f2bf(silu(bs.w + tv.w + xa * wa.w + xb * wb.w));
  *(u16x4*)&h0[(size_t)b * H + n] = r;
}

// --- main GEMM: out = silu(A @ BT^T + bias); A bf16 [1024x1024], BT bf16 [N][K]
// 64x64 tile, 4 waves, K-split per wave, no LDS / no barrier in main loop.
__global__ __launch_bounds__(256) void gemm_mfma(const u16* __restrict__ A,
                                                 const u16* __restrict__ BT,
                                                 const float* __restrict__ bias,
                                                 void* __restrict__ out, int out_bf16) {
  __shared__ float red[4][32][68];  // 34,816 B: cross-wave K-reduction buffer
  const int tid = threadIdx.x;
  const int w = tid >> 6, lane = tid & 63;
  const int lr = lane & 15, quad = lane >> 4;
  const int bn = blockIdx.x, bm = blockIdx.y;

  // wave w owns k in [w*256, w*256+256)
  const u16* Ap = A + (size_t)(bm * 64 + lr) * H + w * 256 + quad * 8;
  const u16* Bp = BT + (size_t)(bn * 64 + lr) * H + w * 256 + quad * 8;

  f32x4 acc[4][4] = {};
  bf16x8 fa[3][4], fb[3][4];  // 3-deep prefetch ring

#define LOADSET(s, koff)                                          \
  {                                                               \
    _Pragma("unroll") for (int q = 0; q < 4; ++q) {               \
      fa[s][q] = *(const bf16x8*)(Ap + q * 16 * H + (koff));      \
      fb[s][q] = *(const bf16x8*)(Bp + q * 16 * H + (koff));      \
    }                                                             \
  }

  LOADSET(0, 0)
  LOADSET(1, 32)
#pragma unroll
  for (int it = 0; it < 8; ++it) {
    const int cur = it % 3;
    if (it < 6) {
      const int nx = (it + 2) % 3;
      LOADSET(nx, (it + 2) * 32)
    }
#pragma unroll
    for (int mt = 0; mt < 4; ++mt)
#pragma unroll
      for (int nt = 0; nt < 4; ++nt)
        acc[mt][nt] = __builtin_amdgcn_mfma_f32_16x16x32_bf16(fa[cur][mt], fb[cur][nt],
                                                              acc[mt][nt], 0, 0, 0);
  }
#undef LOADSET

  // ---- cross-wave reduction + bias + SiLU + store, two 32-row phases ----
  const int m = tid >> 3;          // 0..31 (row within phase)
  const int n0 = (tid & 7) * 8;    // 8 cols per thread
#pragma unroll
  for (int half = 0; half < 2; ++half) {
    if (half) __syncthreads();  // WAR: phase-0 reads done before overwrite
#pragma unroll
    for (int mt = 0; mt < 2; ++mt)
#pragma unroll
      for (int nt = 0; nt < 4; ++nt)
#pragma unroll
        for (int r = 0; r < 4; ++r)
          red[w][mt * 16 + quad * 4 + r][nt * 16 + lr] = acc[half * 2 + mt][nt][r];
    __syncthreads();
    const int gm = bm * 64 + half * 32 + m;
#pragma unroll
    for (int j = 0; j < 2; ++j) {
      const int n = n0 + j * 4;
      f32x4 s0 = *(const f32x4*)&red[0][m][n];
      f32x4 s1 = *(const f32x4*)&red[1][m][n];
      f32x4 s2 = *(const f32x4*)&red[2][m][n];
      f32x4 s3 = *(const f32x4*)&red[3][m][n];
      f32x4 bv = *(const f32x4*)&bias[bn * 64 + n];
      if (out_bf16) {
        u16x4 o;
#pragma unroll
        for (int r = 0; r < 4; ++r)
          o[r] = f2bf(silu(s0[r] + s1[r] + s2[r] + s3[r] + bv[r]));
        *(u16x4*)&((u16*)out)[(size_t)gm * H + bn * 64 + n] = o;
      } else {
        f32x4 o;
#pragma unroll
        for (int r = 0; r < 4; ++r)
          o[r] = silu(s0[r] + s1[r] + s2[r] + s3[r] + bv[r]);
        *(f32x4*)&((float*)out)[(size_t)gm * H + bn * 64 + n] = o;
      }
    }
  }
}

// --- per-step tail: v = h3@W4+b4 ; x += dt*v ; h0(next) = silu(base+tvec+x.W0x)
__global__ void tail_kernel(const float* __restrict__ h3, const float* __restrict__ W4,
                            const float* __restrict__ b4, float* __restrict__ x,
                            const float* __restrict__ base, const float* __restrict__ tvec,
                            const float* __restrict__ W0, u16* __restrict__ h0, int s) {
  const int b = blockIdx.x, tid = threadIdx.x;
  float s0 = 0.0f, s1 = 0.0f;
  for (int h = tid; h < H; h += 256) {
    float v = h3[(size_t)b * H + h];
    s0 += v * W4[2 * h];
    s1 += v * W4[2 * h + 1];
  }
#pragma unroll
  for (int o = 32; o > 0; o >>= 1) {
    s0 += __shfl_down(s0, o);
    s1 += __shfl_down(s1, o);
  }
  __shared__ float red[8];
  __shared__ float xs[2];
  const int w = tid >> 6;
  if ((tid & 63) == 0) { red[w * 2] = s0; red[w * 2 + 1] = s1; }
  __syncthreads();
  if (tid == 0) {
    float v0 = red[0] + red[2] + red[4] + red[6] + b4[0];
    float v1 = red[1] + red[3] + red[5] + red[7] + b4[1];
    float xa = x[2 * b] + DT * v0;
    float xb = x[2 * b + 1] + DT * v1;
    x[2 * b] = xa; x[2 * b + 1] = xb;
    xs[0] = xa; xs[1] = xb;
  }
  __syncthreads();
  if (s < NSTEP - 1) {
    const float xa = xs[0], xb = xs[1];
    const int n = tid * 4;
    float4 bs = *(const float4*)&base[(size_t)b * H + n];
    float4 tv = *(const float4*)&tvec[(size_t)(s + 1) * H + n];
    float4 wa = *(const float4*)&W0[254 * H + n];
    float4 wb = *(const float4*)&W0[255 * H + n];
    u16x4 r;
    r[0] = f2bf(silu(bs.x + tv.x + xa * wa.x + xb * wb.x));
    r[1] = f2bf(silu(bs.y + tv.y + xa * wa.y + xb * wb.y));
    r[2] = f2bf(silu(bs.z + tv.z + xa * wa.z + xb * wb.z));
    r[3] = f2bf(silu(bs.w + tv.w + xa * wa.w + xb * wb.w));
    *(u16x4*)&h0[(size_t)b * H + n] = r;
  }
}

extern "C" void kernel_launch(void* const* d_in, const int* in_sizes, int n_in,
                              void* d_out, int out_size, void* d_ws, size_t ws_size,
                              hipStream_t stream) {
  const float* state = (const float*)d_in[0];
  const float* x0    = (const float*)d_in[1];
  const float* W0    = (const float*)d_in[2];
  const float* b0    = (const float*)d_in[3];
  const float* W1    = (const float*)d_in[4];
  const float* b1    = (const float*)d_in[5];
  const float* W2    = (const float*)d_in[6];
  const float* b2    = (const float*)d_in[7];
  const float* W3    = (const float*)d_in[8];
  const float* b3    = (const float*)d_in[9];
  const float* W4    = (const float*)d_in[10];
  const float* b4    = (const float*)d_in[11];
  float* xout = (float*)d_out;

  char* ws = (char*)d_ws;
  const size_t MB = 1024 * 1024;
  float* base = (float*)(ws + 0);          // 4 MiB
  float* h3f  = (float*)(ws + 4 * MB);     // 4 MiB
  float* tvec = (float*)(ws + 8 * MB);     // 200 KiB (reserve 256 KiB)
  u16* w1t = (u16*)(ws + 8 * MB + 256 * 1024);               // 2 MiB each
  u16* w2t = (u16*)(ws + 10 * MB + 256 * 1024);
  u16* w3t = (u16*)(ws + 12 * MB + 256 * 1024);
  u16* hA  = (u16*)(ws + 14 * MB + 256 * 1024);
  u16* hB  = (u16*)(ws + 16 * MB + 256 * 1024);
  u16* hC  = (u16*)(ws + 18 * MB + 256 * 1024);

  transpose_w<<<dim3(32, 32, 3), 256, 0, stream>>>(W1, W2, W3, w1t, w2t, w3t);
  base_gemm<<<dim3(2, 128), 128, 0, stream>>>(state, W0, b0, base);
  tvec_kernel<<<dim3(NSTEP, 4), 256, 0, stream>>>(W0, tvec);
  init_kernel<<<BATCH, 256, 0, stream>>>(base, tvec, x0, W0, hA, xout);

  for (int s = 0; s < NSTEP; ++s) {
    gemm_mfma<<<dim3(16, 16), 256, 0, stream>>>(hA, w1t, b1, hB, 1);
    gemm_mfma<<<dim3(16, 16), 256, 0, stream>>>(hB, w2t, b2, hC, 1);
    gemm_mfma<<<dim3(16, 16), 256, 0, stream>>>(hC, w3t, b3, h3f, 0);
    tail_kernel<<<BATCH, 256, 0, stream>>>(h3f, W4, b4, xout, base, tvec, W0, hA, s);
  }
}

// Round 2
// 2013.445 us; speedup vs baseline: 1.0543x; 1.0543x over previous
//
#include <hip/hip_runtime.h>

// ---------------------------------------------------------------------------
// FlowMatchingShield: 50-step Euler sampler over a 5-layer MLP.
//   h = concat([state(254), x(2), temb(64)])  -> 320
//   h @ W0 split:  base = state@W0[0:254]+b0  (once)
//                  tvec[s] = temb(s)@W0[256:320] (once, 50 vectors)
//                  x-part = x@W0[254:256]  (elementwise per step)
//   per step: 3x (1024x1024x1024) GEMM+SiLU  [bf16 MFMA]
//             + head W4 (1024->2) + Euler update + next h0  [fp32 fused tail]
//
// GEMM (round 2): 64x64 tile, 512 threads (8 waves), grid 16x16 = 1 block/CU,
// K split 8-ways (128/wave). All 32 fragments (4 k-iters) loaded UP-FRONT ->
// 32 loads in flight per wave, 2 waves/SIMD: latency-bound fix for round 1's
// 1-wave/SIMD depth-2 pipeline. Cross-wave reduction via 34.8 KB LDS in four
// 16-row phases, fused bias+SiLU, coalesced stores.
// base_gemm (round 2): classic fp32 LDS-tile GEMM (64x64 tile, K-chunk 64):
// round 1's version was latency-bound at 5% occupancy.
// ---------------------------------------------------------------------------

typedef __bf16 bf16x8 __attribute__((ext_vector_type(8)));
typedef float  f32x4  __attribute__((ext_vector_type(4)));
typedef float  f32x2  __attribute__((ext_vector_type(2)));
typedef unsigned short u16;
typedef u16 u16x8 __attribute__((ext_vector_type(8)));
typedef u16 u16x4 __attribute__((ext_vector_type(4)));
typedef u16 u16x2 __attribute__((ext_vector_type(2)));

#define H 1024
#define BATCH 1024
#define SDIM 254
#define NSTEP 50
#define DT 0.02f

__device__ __forceinline__ u16 f2bf(float f) {
  unsigned int u = __float_as_uint(f);
  return (u16)((u + 0x7FFFu + ((u >> 16) & 1u)) >> 16);
}

__device__ __forceinline__ float silu(float v) {
  return v / (1.0f + __expf(-v));
}

// --- one-time: W[k][n] fp32 -> WT[n][k] bf16, for W1..W3 (blockIdx.z picks) --
__global__ void transpose_w(const float* __restrict__ A, const float* __restrict__ B,
                            const float* __restrict__ C, u16* __restrict__ TA,
                            u16* __restrict__ TB, u16* __restrict__ TC) {
  const float* W = (blockIdx.z == 0) ? A : (blockIdx.z == 1) ? B : C;
  u16* T = (blockIdx.z == 0) ? TA : (blockIdx.z == 1) ? TB : TC;
  __shared__ float tile[32][33];
  const int n0 = blockIdx.x * 32, k0 = blockIdx.y * 32;
  const int tx = threadIdx.x & 31, ty = threadIdx.x >> 5;  // 32 x 8
#pragma unroll
  for (int i = 0; i < 4; ++i)
    tile[ty + 8 * i][tx] = W[(k0 + ty + 8 * i) * H + n0 + tx];
  __syncthreads();
#pragma unroll
  for (int i = 0; i < 4; ++i)
    T[(size_t)(n0 + ty + 8 * i) * H + k0 + tx] = f2bf(tile[tx][ty + 8 * i]);
}

// --- one-time: base[b][n] = b0[n] + sum_k state[b][k]*W0[k][n] (k<254) -------
// fp32 LDS-tile GEMM: 64x64 output tile, K-chunks of 64 (zero-padded tail).
__global__ __launch_bounds__(256) void base_gemm(const float* __restrict__ state,
                                                 const float* __restrict__ W0,
                                                 const float* __restrict__ b0,
                                                 float* __restrict__ base) {
  __shared__ float Sst[64][68];  // [batch-row][k] (stride 68: 16B-aligned rows)
  __shared__ float Wl[64][68];   // [k][col]
  const int bc = blockIdx.x, br = blockIdx.y, tid = threadIdx.x;
  const int myrow = (tid >> 4) * 4;  // 0..60
  const int mycol = (tid & 15) * 4;  // 0..60
  const int lr = tid >> 2;           // 0..63 (staging row / k)
  const int lc = (tid & 3) * 16;     // staging col group
  f32x4 acc[4] = {};

  for (int kc = 0; kc < 4; ++kc) {
    const int k0 = kc * 64;
    // stage state tile: Sst[r][kk] = state[br*64+r][k0+kk] (zero-pad k>=254)
#pragma unroll
    for (int j = 0; j < 8; ++j) {
      const int k = k0 + lc + 2 * j;
      float vx = 0.f, vy = 0.f;
      if (k + 1 < SDIM) {
        float2 v = *(const float2*)&state[(size_t)(br * 64 + lr) * SDIM + k];
        vx = v.x; vy = v.y;
      } else if (k < SDIM) {
        vx = state[(size_t)(br * 64 + lr) * SDIM + k];
      }
      Sst[lr][lc + 2 * j] = vx;
      Sst[lr][lc + 2 * j + 1] = vy;
    }
    // stage W0 tile: Wl[kk][c] = W0[k0+kk][bc*64+c] (zero-pad kk tail)
#pragma unroll
    for (int j = 0; j < 4; ++j) {
      f32x4 wv = {};
      if (k0 + lr < SDIM)
        wv = *(const f32x4*)&W0[(size_t)(k0 + lr) * H + bc * 64 + lc + 4 * j];
      *(f32x4*)&Wl[lr][lc + 4 * j] = wv;
    }
    __syncthreads();
#pragma unroll 4
    for (int kk = 0; kk < 64; kk += 4) {
      f32x4 sv[4], wv[4];
#pragma unroll
      for (int r = 0; r < 4; ++r) sv[r] = *(const f32x4*)&Sst[myrow + r][kk];
#pragma unroll
      for (int j = 0; j < 4; ++j) wv[j] = *(const f32x4*)&Wl[kk + j][mycol];
#pragma unroll
      for (int r = 0; r < 4; ++r)
#pragma unroll
        for (int j = 0; j < 4; ++j)
          acc[r] += sv[r][j] * wv[j];
    }
    __syncthreads();
  }

  const f32x4 bv = *(const f32x4*)&b0[bc * 64 + mycol];
#pragma unroll
  for (int r = 0; r < 4; ++r) {
    f32x4 o = acc[r] + bv;
    *(f32x4*)&base[(size_t)(br * 64 + myrow + r) * H + bc * 64 + mycol] = o;
  }
}

// --- one-time: tvec[s][h] = sum_j sin(t fj) W0[256+j][h] + cos(t fj) W0[288+j][h]
__global__ void tvec_kernel(const float* __restrict__ W0, float* __restrict__ tvec) {
  const int s = blockIdx.x;
  const int h = blockIdx.y * 256 + threadIdx.x;
  const float t = (float)s * DT;
  float acc = 0.0f;
#pragma unroll
  for (int j = 0; j < 32; ++j) {
    float fr = __expf((float)j * (-9.210340371976184f / 31.0f));
    float ang = t * fr;
    acc += __sinf(ang) * W0[(256 + j) * H + h] + __cosf(ang) * W0[(288 + j) * H + h];
  }
  tvec[s * H + h] = acc;
}

// --- one-time: h0 for step 0 (bf16) + seed x into d_out ----------------------
__global__ void init_kernel(const float* __restrict__ base, const float* __restrict__ tvec,
                            const float* __restrict__ x0, const float* __restrict__ W0,
                            u16* __restrict__ h0, float* __restrict__ xout) {
  const int b = blockIdx.x, tid = threadIdx.x;
  const float xa = x0[2 * b], xb = x0[2 * b + 1];
  if (tid == 0) { xout[2 * b] = xa; xout[2 * b + 1] = xb; }
  const int n = tid * 4;
  float4 bs = *(const float4*)&base[(size_t)b * H + n];
  float4 tv = *(const float4*)&tvec[n];
  float4 wa = *(const float4*)&W0[254 * H + n];
  float4 wb = *(const float4*)&W0[255 * H + n];
  u16x4 r;
  r[0] = f2bf(silu(bs.x + tv.x + xa * wa.x + xb * wb.x));
  r[1] = f2bf(silu(bs.y + tv.y + xa * wa.y + xb * wb.y));
  r[2] = f2bf(silu(bs.z + tv.z + xa * wa.z + xb * wb.z));
  r[3] = f2bf(silu(bs.w + tv.w + xa * wa.w + xb * wb.w));
  *(u16x4*)&h0[(size_t)b * H + n] = r;
}

// --- main GEMM: out = silu(A @ BT^T + bias); A bf16 [1024x1024], BT bf16 [N][K]
// 64x64 tile, 8 waves, K-split 8x128, ALL fragments loaded up-front.
__global__ __launch_bounds__(512, 2) void gemm_mfma(const u16* __restrict__ A,
                                                    const u16* __restrict__ BT,
                                                    const float* __restrict__ bias,
                                                    void* __restrict__ out, int out_bf16) {
  __shared__ float red[8][16][68];  // 34,816 B: cross-wave K-reduction buffer
  const int tid = threadIdx.x;
  const int w = tid >> 6, lane = tid & 63;
  const int lr = lane & 15, quad = lane >> 4;
  const int bn = blockIdx.x, bm = blockIdx.y;

  // wave w owns k in [w*128, w*128+128): 4 k-iters of 32
  const u16* Ap = A + (size_t)(bm * 64 + lr) * H + w * 128 + quad * 8;
  const u16* Bp = BT + (size_t)(bn * 64 + lr) * H + w * 128 + quad * 8;

  bf16x8 fa[4][4], fb[4][4];  // [k-iter][frag] — all live, ~128 VGPR
#pragma unroll
  for (int it = 0; it < 4; ++it)
#pragma unroll
    for (int q = 0; q < 4; ++q) {
      fa[it][q] = *(const bf16x8*)(Ap + q * 16 * H + it * 32);
      fb[it][q] = *(const bf16x8*)(Bp + q * 16 * H + it * 32);
    }

  f32x4 acc[4][4] = {};
#pragma unroll
  for (int it = 0; it < 4; ++it)
#pragma unroll
    for (int mt = 0; mt < 4; ++mt)
#pragma unroll
      for (int nt = 0; nt < 4; ++nt)
        acc[mt][nt] = __builtin_amdgcn_mfma_f32_16x16x32_bf16(fa[it][mt], fb[it][nt],
                                                              acc[mt][nt], 0, 0, 0);

  // ---- cross-wave reduction + bias + SiLU + store, four 16-row phases ----
  const int m = tid >> 5;          // 0..15 (row within phase)
  const int n0 = (tid & 31) * 2;   // 2 cols per thread
  const f32x2 bv = *(const f32x2*)&bias[bn * 64 + n0];
#pragma unroll
  for (int p = 0; p < 4; ++p) {
    if (p) __syncthreads();  // WAR: previous phase reads done before overwrite
#pragma unroll
    for (int nt = 0; nt < 4; ++nt)
#pragma unroll
      for (int r = 0; r < 4; ++r)
        red[w][quad * 4 + r][nt * 16 + lr] = acc[p][nt][r];
    __syncthreads();
    f32x2 s = {};
#pragma unroll
    for (int ww = 0; ww < 8; ++ww) s += *(const f32x2*)&red[ww][m][n0];
    const int gm = bm * 64 + p * 16 + m;
    const float v0 = silu(s[0] + bv[0]);
    const float v1 = silu(s[1] + bv[1]);
    if (out_bf16) {
      u16x2 o = {f2bf(v0), f2bf(v1)};
      *(u16x2*)&((u16*)out)[(size_t)gm * H + bn * 64 + n0] = o;
    } else {
      f32x2 o = {v0, v1};
      *(f32x2*)&((float*)out)[(size_t)gm * H + bn * 64 + n0] = o;
    }
  }
}

// --- per-step tail: v = h3@W4+b4 ; x += dt*v ; h0(next) = silu(base+tvec+x.W0x)
__global__ void tail_kernel(const float* __restrict__ h3, const float* __restrict__ W4,
                            const float* __restrict__ b4, float* __restrict__ x,
                            const float* __restrict__ base, const float* __restrict__ tvec,
                            const float* __restrict__ W0, u16* __restrict__ h0, int s) {
  const int b = blockIdx.x, tid = threadIdx.x;
  float s0 = 0.0f, s1 = 0.0f;
  for (int h = tid; h < H; h += 256) {
    float v = h3[(size_t)b * H + h];
    s0 += v * W4[2 * h];
    s1 += v * W4[2 * h + 1];
  }
#pragma unroll
  for (int o = 32; o > 0; o >>= 1) {
    s0 += __shfl_down(s0, o);
    s1 += __shfl_down(s1, o);
  }
  __shared__ float red[8];
  __shared__ float xs[2];
  const int w = tid >> 6;
  if ((tid & 63) == 0) { red[w * 2] = s0; red[w * 2 + 1] = s1; }
  __syncthreads();
  if (tid == 0) {
    float v0 = red[0] + red[2] + red[4] + red[6] + b4[0];
    float v1 = red[1] + red[3] + red[5] + red[7] + b4[1];
    float xa = x[2 * b] + DT * v0;
    float xb = x[2 * b + 1] + DT * v1;
    x[2 * b] = xa; x[2 * b + 1] = xb;
    xs[0] = xa; xs[1] = xb;
  }
  __syncthreads();
  if (s < NSTEP - 1) {
    const float xa = xs[0], xb = xs[1];
    const int n = tid * 4;
    float4 bs = *(const float4*)&base[(size_t)b * H + n];
    float4 tv = *(const float4*)&tvec[(size_t)(s + 1) * H + n];
    float4 wa = *(const float4*)&W0[254 * H + n];
    float4 wb = *(const float4*)&W0[255 * H + n];
    u16x4 r;
    r[0] = f2bf(silu(bs.x + tv.x + xa * wa.x + xb * wb.x));
    r[1] = f2bf(silu(bs.y + tv.y + xa * wa.y + xb * wb.y));
    r[2] = f2bf(silu(bs.z + tv.z + xa * wa.z + xb * wb.z));
    r[3] = f2bf(silu(bs.w + tv.w + xa * wa.w + xb * wb.w));
    *(u16x4*)&h0[(size_t)b * H + n] = r;
  }
}

extern "C" void kernel_launch(void* const* d_in, const int* in_sizes, int n_in,
                              void* d_out, int out_size, void* d_ws, size_t ws_size,
                              hipStream_t stream) {
  const float* state = (const float*)d_in[0];
  const float* x0    = (const float*)d_in[1];
  const float* W0    = (const float*)d_in[2];
  const float* b0    = (const float*)d_in[3];
  const float* W1    = (const float*)d_in[4];
  const float* b1    = (const float*)d_in[5];
  const float* W2    = (const float*)d_in[6];
  const float* b2    = (const float*)d_in[7];
  const float* W3    = (const float*)d_in[8];
  const float* b3    = (const float*)d_in[9];
  const float* W4    = (const float*)d_in[10];
  const float* b4    = (const float*)d_in[11];
  float* xout = (float*)d_out;

  char* ws = (char*)d_ws;
  const size_t MB = 1024 * 1024;
  float* base = (float*)(ws + 0);          // 4 MiB
  float* h3f  = (float*)(ws + 4 * MB);     // 4 MiB
  float* tvec = (float*)(ws + 8 * MB);     // 200 KiB (reserve 256 KiB)
  u16* w1t = (u16*)(ws + 8 * MB + 256 * 1024);               // 2 MiB each
  u16* w2t = (u16*)(ws + 10 * MB + 256 * 1024);
  u16* w3t = (u16*)(ws + 12 * MB + 256 * 1024);
  u16* hA  = (u16*)(ws + 14 * MB + 256 * 1024);
  u16* hB  = (u16*)(ws + 16 * MB + 256 * 1024);
  u16* hC  = (u16*)(ws + 18 * MB + 256 * 1024);

  transpose_w<<<dim3(32, 32, 3), 256, 0, stream>>>(W1, W2, W3, w1t, w2t, w3t);
  base_gemm<<<dim3(16, 16), 256, 0, stream>>>(state, W0, b0, base);
  tvec_kernel<<<dim3(NSTEP, 4), 256, 0, stream>>>(W0, tvec);
  init_kernel<<<BATCH, 256, 0, stream>>>(base, tvec, x0, W0, hA, xout);

  for (int s = 0; s < NSTEP; ++s) {
    gemm_mfma<<<dim3(16, 16), 512, 0, stream>>>(hA, w1t, b1, hB, 1);
    gemm_mfma<<<dim3(16, 16), 512, 0, stream>>>(hB, w2t, b2, hC, 1);
    gemm_mfma<<<dim3(16, 16), 512, 0, stream>>>(hC, w3t, b3, h3f, 0);
    tail_kernel<<<BATCH, 256, 0, stream>>>(h3f, W4, b4, xout, base, tvec, W0, hA, s);
  }
}